// Round 1
// baseline (143.339 us; speedup 1.0000x reference)
//
#include <hip/hip_runtime.h>

// PositionalCharacterLevelWordSparse:
//   rows = B*W = 65536, L = 16 chars/row, D = 512 + 16 = 528 bins/row.
//   out[row, tok[row,c]]       += (tok != 0)
//   out[row, 512 + pos[row,c]] += (tok != 0)
// Strategy: per-block LDS histograms (8 rows/block), then coalesced float4
// writes. Write-bound: ~138 MB out, ~8 MB in.

constexpr int NUM_EMB = 512;
constexpr int MAX_POS = 16;
constexpr int D = NUM_EMB + MAX_POS;   // 528
constexpr int L = 16;
constexpr int ROWS_PER_BLOCK = 8;
constexpr int THREADS = 256;
constexpr int HIST_INTS = ROWS_PER_BLOCK * D;       // 4224
constexpr int HIST_VEC4 = HIST_INTS / 4;            // 1056

__global__ __launch_bounds__(THREADS)
void pcls_hist_kernel(const int* __restrict__ tok,
                      const int* __restrict__ pos,
                      float* __restrict__ out) {
    __shared__ int hist[HIST_INTS];

    const int tid = threadIdx.x;
    const long long row_base = (long long)blockIdx.x * ROWS_PER_BLOCK;

    // Phase 1: zero the LDS histograms (int4-wide).
    int4* h4 = reinterpret_cast<int4*>(hist);
    for (int i = tid; i < HIST_VEC4; i += THREADS)
        h4[i] = make_int4(0, 0, 0, 0);
    __syncthreads();

    // Phase 2: scatter. 128 threads each own one (row, char) slot.
    if (tid < ROWS_PER_BLOCK * L) {
        const long long g = row_base * L + tid;
        const int t = tok[g];
        const int p = pos[g];
        if (t != 0) {                      // PADDING_IDX mask (masks BOTH adds)
            const int r = tid / L;         // 0..7 row within block
            atomicAdd(&hist[r * D + t], 1);
            atomicAdd(&hist[r * D + NUM_EMB + p], 1);
        }
    }
    __syncthreads();

    // Phase 3: stream histograms to global as float4 (coalesced).
    float4* out4 = reinterpret_cast<float4*>(out + row_base * D);
    for (int i = tid; i < HIST_VEC4; i += THREADS) {
        const int4 v = h4[i];
        out4[i] = make_float4((float)v.x, (float)v.y, (float)v.z, (float)v.w);
    }
}

extern "C" void kernel_launch(void* const* d_in, const int* in_sizes, int n_in,
                              void* d_out, int out_size, void* d_ws, size_t ws_size,
                              hipStream_t stream) {
    const int* tok = (const int*)d_in[0];
    const int* pos = (const int*)d_in[1];
    float* out = (float*)d_out;

    const int n_rows = in_sizes[0] / L;              // 65536
    const int grid = n_rows / ROWS_PER_BLOCK;        // 8192 (exact: 65536 % 8 == 0)

    pcls_hist_kernel<<<grid, THREADS, 0, stream>>>(tok, pos, out);
}